// Round 3
// baseline (54.633 us; speedup 1.0000x reference)
//
#include <hip/hip_runtime.h>
#include <cmath>

// Problem constants (fixed by setup_inputs)
#define KS     25
#define HALF   12
#define N_IN   16384
#define N_OUT  8192     // N_IN / STRIDE
#define C_DIM  128
#define B_DIM  16

#define OPT    16                   // outputs per thread
#define TPB    256
#define OUT_PER_BLOCK (OPT * TPB)   // 4096
#define SEGS   (N_OUT / OUT_PER_BLOCK)  // 2
#define NV     (2 * OPT + KS - 1 + 1)   // 56 input floats per thread (float4-aligned)

typedef float f32x4 __attribute__((ext_vector_type(4)));

__global__ __launch_bounds__(TPB) void parabolic_pool_kernel(
    const float* __restrict__ f,
    const float* __restrict__ t,
    float* __restrict__ out) {

  const int blk = blockIdx.x;
  const int seg = blk & (SEGS - 1);
  const int row = blk >> 1;            // b*C + c
  const int c   = row & (C_DIM - 1);

  const float* __restrict__ frow = f + (size_t)row * N_IN;
  float* __restrict__ orow       = out + (size_t)row * N_OUT;

  const int o_t   = seg * OUT_PER_BLOCK + (int)threadIdx.x * OPT;
  const int jbase = 2 * o_t - HALF;    // first input index needed; ≡ 0 (mod 4)

  // Issue all loads up front so they pipeline.
  float v[NV];
  if (jbase >= 0 && jbase + NV <= N_IN) {
    // fast path: 14 coalesced float4 loads
#pragma unroll
    for (int q = 0; q < NV / 4; ++q) {
      const f32x4 x = *reinterpret_cast<const f32x4*>(frow + jbase + 4 * q);
      v[4 * q + 0] = x.x;
      v[4 * q + 1] = x.y;
      v[4 * q + 2] = x.z;
      v[4 * q + 3] = x.w;
    }
  } else {
    // boundary path (2 threads per row): guarded scalar loads, -inf pad
#pragma unroll
    for (int k = 0; k < NV; ++k) {
      const int j = jbase + k;
      v[k] = (j >= 0 && j < N_IN) ? frow[j] : -INFINITY;
    }
  }

  // h[d] = -(d-12)^2 / (4*t[c])  computed as (d-12)^2 * (-0.25/t)
  const float minv = -0.25f / t[c];
  float h[KS];
#pragma unroll
  for (int d = 0; d < KS; ++d) {
    const float z = (float)(d - HALF);
    h[d] = (z * z) * minv;
  }

  float acc[OPT];
#pragma unroll
  for (int o = 0; o < OPT; ++o) {
    float m = v[2 * o] + h[0];
#pragma unroll
    for (int d = 1; d < KS; ++d) {
      m = fmaxf(m, v[2 * o + d] + h[d]);
    }
    acc[o] = m;
  }

  // 4 coalesced float4 non-temporal stores (output never re-read)
#pragma unroll
  for (int q = 0; q < OPT / 4; ++q) {
    f32x4 s;
    s.x = acc[4 * q + 0];
    s.y = acc[4 * q + 1];
    s.z = acc[4 * q + 2];
    s.w = acc[4 * q + 3];
    __builtin_nontemporal_store(s, reinterpret_cast<f32x4*>(orow + o_t + 4 * q));
  }
}

extern "C" void kernel_launch(void* const* d_in, const int* in_sizes, int n_in,
                              void* d_out, int out_size, void* d_ws, size_t ws_size,
                              hipStream_t stream) {
  const float* f = (const float*)d_in[0];   // (16, 128, 16384) f32
  const float* t = (const float*)d_in[1];   // (128,) f32
  float* out     = (float*)d_out;           // (16, 128, 8192) f32

  const int grid = B_DIM * C_DIM * SEGS;    // 4096 blocks
  parabolic_pool_kernel<<<grid, TPB, 0, stream>>>(f, t, out);
}

// Round 4
// 49.649 us; speedup vs baseline: 1.1004x; 1.1004x over previous
//
#include <hip/hip_runtime.h>
#include <cmath>

// Problem constants (fixed by setup_inputs)
#define KS     25
#define HALF   12
#define N_IN   16384
#define N_OUT  8192     // N_IN / STRIDE
#define C_DIM  128
#define B_DIM  16

#define OPT    16                   // outputs per thread
#define TPB    256
#define OUT_PER_BLOCK (OPT * TPB)   // 4096
#define SEGS   (N_OUT / OUT_PER_BLOCK)  // 2
#define NV     (2 * OPT + KS - 1 + 1)   // 56 input floats per thread (float4-aligned)

typedef float f32x4 __attribute__((ext_vector_type(4)));

__global__ __launch_bounds__(TPB) void parabolic_pool_kernel(
    const float* __restrict__ f,
    const float* __restrict__ t,
    float* __restrict__ out) {

  const int blk = blockIdx.x;
  const int seg = blk & (SEGS - 1);
  const int row = blk >> 1;            // b*C + c
  const int c   = row & (C_DIM - 1);

  const float* __restrict__ frow = f + (size_t)row * N_IN;
  float* __restrict__ orow       = out + (size_t)row * N_OUT;

  const int o_t   = seg * OUT_PER_BLOCK + (int)threadIdx.x * OPT;
  const int jbase = 2 * o_t - HALF;    // first input index needed; ≡ 0 (mod 4)

  // Issue all loads up front so they pipeline.
  float v[NV];
  if (jbase >= 0 && jbase + NV <= N_IN) {
    // fast path: 14 coalesced float4 loads
#pragma unroll
    for (int q = 0; q < NV / 4; ++q) {
      const f32x4 x = *reinterpret_cast<const f32x4*>(frow + jbase + 4 * q);
      v[4 * q + 0] = x.x;
      v[4 * q + 1] = x.y;
      v[4 * q + 2] = x.z;
      v[4 * q + 3] = x.w;
    }
  } else {
    // boundary path (2 threads per row): guarded scalar loads, -inf pad
#pragma unroll
    for (int k = 0; k < NV; ++k) {
      const int j = jbase + k;
      v[k] = (j >= 0 && j < N_IN) ? frow[j] : -INFINITY;
    }
  }

  // h[d] = -(d-12)^2 / (4*t[c])  computed as (d-12)^2 * (-0.25/t)
  const float minv = -0.25f / t[c];
  float h[KS];
#pragma unroll
  for (int d = 0; d < KS; ++d) {
    const float z = (float)(d - HALF);
    h[d] = (z * z) * minv;
  }

  float acc[OPT];
#pragma unroll
  for (int o = 0; o < OPT; ++o) {
    float m = v[2 * o] + h[0];
#pragma unroll
    for (int d = 1; d < KS; ++d) {
      m = fmaxf(m, v[2 * o + d] + h[d]);
    }
    acc[o] = m;
  }

  // 4 coalesced float4 stores (normal path — L2 write-combining matters)
#pragma unroll
  for (int q = 0; q < OPT / 4; ++q) {
    f32x4 s;
    s.x = acc[4 * q + 0];
    s.y = acc[4 * q + 1];
    s.z = acc[4 * q + 2];
    s.w = acc[4 * q + 3];
    *reinterpret_cast<f32x4*>(orow + o_t + 4 * q) = s;
  }
}

extern "C" void kernel_launch(void* const* d_in, const int* in_sizes, int n_in,
                              void* d_out, int out_size, void* d_ws, size_t ws_size,
                              hipStream_t stream) {
  const float* f = (const float*)d_in[0];   // (16, 128, 16384) f32
  const float* t = (const float*)d_in[1];   // (128,) f32
  float* out     = (float*)d_out;           // (16, 128, 8192) f32

  const int grid = B_DIM * C_DIM * SEGS;    // 4096 blocks
  parabolic_pool_kernel<<<grid, TPB, 0, stream>>>(f, t, out);
}

// Round 5
// 39.087 us; speedup vs baseline: 1.3977x; 1.2702x over previous
//
#include <hip/hip_runtime.h>
#include <cmath>

// Problem constants (fixed by setup_inputs)
#define KS     25
#define HALF   12
#define N_IN   16384
#define N_OUT  8192     // N_IN / STRIDE
#define C_DIM  128
#define B_DIM  16

#define OPT    8                        // outputs per thread
#define TPB    256
#define OUT_BLK (OPT * TPB)             // 2048 outputs per block
#define SEGS   (N_OUT / OUT_BLK)        // 4
#define NF     4128                     // staged floats per block (16-aligned, >= 2*2047+25)
#define NGRAN  (NF / 4)                 // 1032 float4 granules
#define LDS_F  (NF + NF / 16)           // +1 float pad per 16 -> 4386

typedef float f32x4 __attribute__((ext_vector_type(4)));

__global__ __launch_bounds__(TPB) void parabolic_pool_kernel(
    const float* __restrict__ f,
    const float* __restrict__ t,
    float* __restrict__ out) {

  __shared__ float lds[LDS_F];

  const int blk = blockIdx.x;
  const int seg = blk & (SEGS - 1);
  const int row = blk >> 2;            // b*C + c
  const int c   = row & (C_DIM - 1);
  const int tid = threadIdx.x;

  const float* __restrict__ frow = f + (size_t)row * N_IN;
  float* __restrict__ orow       = out + (size_t)row * N_OUT;

  const int o0    = seg * OUT_BLK;
  const int gbase = 2 * o0 - HALF;     // global float index of lds[0] (pre-pad)

  // ---- Stage: dense, fully-coalesced global loads (1.0x unique traffic) ----
  // granule g covers block-local floats [4g, 4g+4); padded LDS addr = 4g + (g>>2)
#pragma unroll
  for (int i = 0; i < (NGRAN + TPB - 1) / TPB; ++i) {
    const int g = i * TPB + tid;
    if (g < NGRAN) {
      const int j  = 4 * g;
      const int p  = j + (g >> 2);
      const int gf = gbase + j;
      if (gf >= 0 && gf + 4 <= N_IN) {
        *reinterpret_cast<f32x4*>(&lds[p]) =
            *reinterpret_cast<const f32x4*>(frow + gf);
      } else {
#pragma unroll
        for (int k = 0; k < 4; ++k) {
          const int jj = gf + k;
          lds[p + k] = (jj >= 0 && jj < N_IN) ? frow[jj] : -INFINITY;
        }
      }
    }
  }

  // h[d] = -(d-12)^2 / (4*t[c])  computed as (d-12)^2 * (-0.25/t)
  const float minv = -0.25f / t[c];
  float h[KS];
#pragma unroll
  for (int d = 0; d < KS; ++d) {
    const float z = (float)(d - HALF);
    h[d] = (z * z) * minv;
  }

  __syncthreads();

  // ---- Window read from LDS: 10x ds_read_b128, stride-17 => conflict-free ----
  // local window start j0 = 16*tid; padded base for group m: 17*(tid+m)
  float w[40];
#pragma unroll
  for (int m = 0; m < 2; ++m) {
    const int p = 17 * (tid + m);
#pragma unroll
    for (int q = 0; q < 4; ++q) {
      const f32x4 x = *reinterpret_cast<const f32x4*>(&lds[p + 4 * q]);
      w[16 * m + 4 * q + 0] = x.x;
      w[16 * m + 4 * q + 1] = x.y;
      w[16 * m + 4 * q + 2] = x.z;
      w[16 * m + 4 * q + 3] = x.w;
    }
  }
  {
    const int p = 17 * (tid + 2);
#pragma unroll
    for (int q = 0; q < 2; ++q) {
      const f32x4 x = *reinterpret_cast<const f32x4*>(&lds[p + 4 * q]);
      w[32 + 4 * q + 0] = x.x;
      w[32 + 4 * q + 1] = x.y;
      w[32 + 4 * q + 2] = x.z;
      w[32 + 4 * q + 3] = x.w;
    }
  }

  // ---- Compute ----
  float acc[OPT];
#pragma unroll
  for (int o = 0; o < OPT; ++o) {
    float m = w[2 * o] + h[0];
#pragma unroll
    for (int d = 1; d < KS; ++d) {
      m = fmaxf(m, w[2 * o + d] + h[d]);
    }
    acc[o] = m;
  }

  // ---- Store: 2 coalesced float4 stores ----
  const int o_t = o0 + tid * OPT;
  *reinterpret_cast<f32x4*>(orow + o_t) =
      (f32x4){acc[0], acc[1], acc[2], acc[3]};
  *reinterpret_cast<f32x4*>(orow + o_t + 4) =
      (f32x4){acc[4], acc[5], acc[6], acc[7]};
}

extern "C" void kernel_launch(void* const* d_in, const int* in_sizes, int n_in,
                              void* d_out, int out_size, void* d_ws, size_t ws_size,
                              hipStream_t stream) {
  const float* f = (const float*)d_in[0];   // (16, 128, 16384) f32
  const float* t = (const float*)d_in[1];   // (128,) f32
  float* out     = (float*)d_out;           // (16, 128, 8192) f32

  const int grid = B_DIM * C_DIM * SEGS;    // 8192 blocks
  parabolic_pool_kernel<<<grid, TPB, 0, stream>>>(f, t, out);
}

// Round 6
// 36.663 us; speedup vs baseline: 1.4902x; 1.0661x over previous
//
#include <hip/hip_runtime.h>
#include <cmath>

// Problem constants (fixed by setup_inputs)
#define KS     25
#define HALF   12
#define N_IN   16384
#define N_OUT  8192     // N_IN / STRIDE
#define C_DIM  128
#define B_DIM  16

#define OPT    8                    // outputs per thread
#define TPB    256
#define OUT_PER_BLOCK (OPT * TPB)   // 2048
#define SEGS   (N_OUT / OUT_PER_BLOCK)  // 4
#define NV     (2 * OPT + KS - 1 + 1)   // 40 input floats per thread

__global__ __launch_bounds__(TPB) void parabolic_pool_kernel(
    const float* __restrict__ f,
    const float* __restrict__ t,
    float* __restrict__ out) {

  const int blk = blockIdx.x;
  const int seg = blk & (SEGS - 1);
  const int row = blk >> 2;            // b*C + c
  const int c   = row & (C_DIM - 1);

  const float* __restrict__ frow = f + (size_t)row * N_IN;
  float* __restrict__ orow       = out + (size_t)row * N_OUT;

  // h[d] = -(d-12)^2 / (4*t[c])  computed as (d-12)^2 * (-0.25/t)
  const float tc   = t[c];
  const float minv = -0.25f / tc;
  float h[KS];
#pragma unroll
  for (int d = 0; d < KS; ++d) {
    const float z = (float)(d - HALF);
    h[d] = (z * z) * minv;
  }

  const int o_t   = seg * OUT_PER_BLOCK + (int)threadIdx.x * OPT;
  const int jbase = 2 * o_t - HALF;    // first input index needed (float4-aligned)

  float v[NV];
  if (jbase >= 0 && jbase + NV <= N_IN) {
    // fast path: 10 coalesced float4 loads
#pragma unroll
    for (int q = 0; q < NV / 4; ++q) {
      const float4 x = *reinterpret_cast<const float4*>(frow + jbase + 4 * q);
      v[4 * q + 0] = x.x;
      v[4 * q + 1] = x.y;
      v[4 * q + 2] = x.z;
      v[4 * q + 3] = x.w;
    }
  } else {
    // boundary path (2 threads per row): guarded scalar loads, -inf pad
#pragma unroll
    for (int k = 0; k < NV; ++k) {
      const int j = jbase + k;
      v[k] = (j >= 0 && j < N_IN) ? frow[j] : -INFINITY;
    }
  }

  float acc[OPT];
#pragma unroll
  for (int o = 0; o < OPT; ++o) {
    float m = v[2 * o] + h[0];
#pragma unroll
    for (int d = 1; d < KS; ++d) {
      m = fmaxf(m, v[2 * o + d] + h[d]);
    }
    acc[o] = m;
  }

  // two coalesced float4 stores (o_t is a multiple of 8)
  *reinterpret_cast<float4*>(orow + o_t) =
      make_float4(acc[0], acc[1], acc[2], acc[3]);
  *reinterpret_cast<float4*>(orow + o_t + 4) =
      make_float4(acc[4], acc[5], acc[6], acc[7]);
}

extern "C" void kernel_launch(void* const* d_in, const int* in_sizes, int n_in,
                              void* d_out, int out_size, void* d_ws, size_t ws_size,
                              hipStream_t stream) {
  const float* f = (const float*)d_in[0];   // (16, 128, 16384) f32
  const float* t = (const float*)d_in[1];   // (128,) f32
  float* out     = (float*)d_out;           // (16, 128, 8192) f32

  const int grid = B_DIM * C_DIM * SEGS;    // 8192 blocks
  parabolic_pool_kernel<<<grid, TPB, 0, stream>>>(f, t, out);
}